// Round 5
// baseline (3325.863 us; speedup 1.0000x reference)
//
#include <hip/hip_runtime.h>
#include <hip/hip_bf16.h>

// B=2, N=2048, D=1024, H=16, DH=64.
// R5: identical to R4 except the FINAL OUTPUT IS WRITTEN AS FP32 (the reference's
// output dtype). Evidence: R3/R4 produced bit-identical absmax 1.882812 with two
// unrelated attention kernels => common format bug; stub absmax 1.5625 = max|ref|.
// Input dtype (fp32 vs bf16) still runtime-detected per-kernel.
//
// ws (bf16 elems): Q[B][H][N][DH]@0, K@4M, V@8M, AO[B][N][H*DH]@12M. 32 MB.

typedef __bf16 bf16x8 __attribute__((ext_vector_type(8)));
typedef float f32x4 __attribute__((ext_vector_type(4)));
typedef unsigned short ushort_t;

#define MFMA_16x16x32(a, b, c) __builtin_amdgcn_mfma_f32_16x16x32_bf16(a, b, c, 0, 0, 0)

__device__ __forceinline__ ushort_t f2bf(float f) {
    __hip_bfloat16 h = __float2bfloat16(f);
    return __builtin_bit_cast(ushort_t, h);
}
__device__ __forceinline__ float bf2f(ushort_t u) {
    unsigned x = ((unsigned)u) << 16;
    return __builtin_bit_cast(float, x);
}

// Wave-uniform dtype probe: weights ~N(0, 0.02^2) -> bf16 words never have
// exp-field >= 0x7F; fp32 low-mantissa words are ~uniform -> ~50% hit.
__device__ __forceinline__ unsigned detect_fp32(const void* wp) {
    const ushort_t* w = (const ushort_t*)wp;
    unsigned c = 0;
    #pragma unroll
    for (int i = 0; i < 128; ++i) c += (((w[i] >> 7) & 0xFF) >= 0x7F) ? 1u : 0u;
    return (c > 8) ? 1u : 0u;
}

// Load 8 consecutive elements (idx multiple of 8) as bf16 packed in uint4.
__device__ __forceinline__ uint4 load8(const void* p, size_t idx, unsigned flag) {
    if (flag) {
        const float* f = (const float*)p + idx;
        float4 a = *(const float4*)f;
        float4 b = *(const float4*)(f + 4);
        ushort_t u[8] = { f2bf(a.x), f2bf(a.y), f2bf(a.z), f2bf(a.w),
                          f2bf(b.x), f2bf(b.y), f2bf(b.z), f2bf(b.w) };
        return *(uint4*)u;
    }
    return *(const uint4*)((const ushort_t*)p + idx);
}

// ---------------- QKV projection GEMM ----------------
// grid (16 n-tiles, 64 m-tiles, 3 weights), block 256 (4 waves), 64x64 tile, BK=32.
// Outputs Q,K,V all in [B][H][N][DH].
__global__ __launch_bounds__(256) void qkv_gemm(
    const void* __restrict__ X, const void* __restrict__ Wq,
    const void* __restrict__ Wk, const void* __restrict__ Wv,
    ushort_t* __restrict__ Q, ushort_t* __restrict__ K, ushort_t* __restrict__ V)
{
    __shared__ ushort_t As[64 * 40];
    __shared__ ushort_t Bs[64 * 40];   // transposed: Bs[n][k]

    const unsigned flag = detect_fp32(Wq);
    const int z = blockIdx.z;
    const void* W = (z == 0) ? Wq : ((z == 1) ? Wk : Wv);

    const int tid  = threadIdx.x;
    const int m0   = blockIdx.y * 64, n0 = blockIdx.x * 64;
    const int lane = tid & 63, wv = tid >> 6;
    const int quad = lane >> 4, l15 = lane & 15;
    const int wm = (wv & 1) * 32, wn = (wv >> 1) * 32;

    const int ar = tid >> 2, ac = (tid & 3) * 8;
    const int bk = tid >> 3, bc = (tid & 7) * 8;

    f32x4 acc[2][2] = {};

    uint4 ra = load8(X, (size_t)(m0 + ar) * 1024 + ac, flag);
    uint4 rb = load8(W, (size_t)bk * 1024 + n0 + bc, flag);

    for (int kt = 0; kt < 32; ++kt) {
        __syncthreads();
        *(uint4*)(As + ar * 40 + ac) = ra;
        {
            const ushort_t* s = (const ushort_t*)&rb;
            #pragma unroll
            for (int i = 0; i < 8; ++i) Bs[(bc + i) * 40 + bk] = s[i];
        }
        __syncthreads();
        if (kt < 31) {
            int k0 = (kt + 1) * 32;
            ra = load8(X, (size_t)(m0 + ar) * 1024 + k0 + ac, flag);
            rb = load8(W, (size_t)(k0 + bk) * 1024 + n0 + bc, flag);
        }
        bf16x8 af0 = *(const bf16x8*)(As + (wm + l15) * 40 + quad * 8);
        bf16x8 af1 = *(const bf16x8*)(As + (wm + 16 + l15) * 40 + quad * 8);
        bf16x8 bf0 = *(const bf16x8*)(Bs + (wn + l15) * 40 + quad * 8);
        bf16x8 bf1 = *(const bf16x8*)(Bs + (wn + 16 + l15) * 40 + quad * 8);
        acc[0][0] = MFMA_16x16x32(af0, bf0, acc[0][0]);
        acc[0][1] = MFMA_16x16x32(af0, bf1, acc[0][1]);
        acc[1][0] = MFMA_16x16x32(af1, bf0, acc[1][0]);
        acc[1][1] = MFMA_16x16x32(af1, bf1, acc[1][1]);
    }

    // C/D layout: row=(quad*4+r), col=l15 within each 16x16 subtile.
    ushort_t* dst = (z == 0) ? Q : ((z == 1) ? K : V);
    #pragma unroll
    for (int mm = 0; mm < 2; ++mm) {
        #pragma unroll
        for (int nn = 0; nn < 2; ++nn) {
            #pragma unroll
            for (int r = 0; r < 4; ++r) {
                int m = m0 + wm + mm * 16 + quad * 4 + r;
                int c = n0 + wn + nn * 16 + l15;
                int b = m >> 11, nseq = m & 2047;
                int h = c >> 6, dh = c & 63;
                dst[((size_t)((b * 16 + h) * 2048 + nseq)) * 64 + dh] = f2bf(acc[mm][nn][r]);
            }
        }
    }
}

// ---------------- Scalar flash attention with ALiBi, causal ----------------
// grid (B*H=32, N/256=8), block 256; thread t owns q-row i. fp32 math.
// weight = exp2(qk*scale*log2e - slope*log2e*j); l > 0 guaranteed (j=0 term).
__global__ __launch_bounds__(256) void attn_simple(
    const ushort_t* __restrict__ Q, const ushort_t* __restrict__ K,
    const ushort_t* __restrict__ V, ushort_t* __restrict__ AO)
{
    __shared__ float Ks[64][65];
    __shared__ float Vs[64][65];

    const int tid = threadIdx.x;
    const int bh  = blockIdx.x, h = bh & 15, b = bh >> 4;
    const int i   = blockIdx.y * 256 + tid;

    const ushort_t* Qh = Q + (size_t)bh * 2048 * 64;
    const ushort_t* Kh = K + (size_t)bh * 2048 * 64;
    const ushort_t* Vh = V + (size_t)bh * 2048 * 64;

    const float LOG2E = 1.44269504088896340736f;
    const float sl2 = exp2f(-0.5f * (float)(h + 1)) * LOG2E;   // slope*log2e
    const float c1  = 0.125f * LOG2E;                          // DH^-0.5*log2e

    float q[64];
    #pragma unroll
    for (int d0 = 0; d0 < 64; d0 += 8) {
        uint4 t = *(const uint4*)(Qh + (size_t)i * 64 + d0);
        const ushort_t* s = (const ushort_t*)&t;
        #pragma unroll
        for (int e = 0; e < 8; ++e) q[d0 + e] = bf2f(s[e]);
    }

    float o[64] = {};
    float l = 0.0f;

    const int ntiles = (blockIdx.y * 256 + 255) / 64 + 1;
    for (int jt = 0; jt < ntiles; ++jt) {
        const int j0 = jt * 64;
        __syncthreads();
        {
            int row = tid >> 2, seg = (tid & 3) * 16;
            #pragma unroll
            for (int half = 0; half < 2; ++half) {
                uint4 tk = *(const uint4*)(Kh + (size_t)(j0 + row) * 64 + seg + half * 8);
                uint4 tv = *(const uint4*)(Vh + (size_t)(j0 + row) * 64 + seg + half * 8);
                const ushort_t* sk = (const ushort_t*)&tk;
                const ushort_t* sv = (const ushort_t*)&tv;
                #pragma unroll
                for (int e = 0; e < 8; ++e) {
                    Ks[row][seg + half * 8 + e] = bf2f(sk[e]);
                    Vs[row][seg + half * 8 + e] = bf2f(sv[e]);
                }
            }
        }
        __syncthreads();
        const int jmax = min(64, i - j0 + 1);
        for (int jj = 0; jj < jmax; ++jj) {
            float s = 0.0f;
            #pragma unroll
            for (int d = 0; d < 64; ++d) s = fmaf(q[d], Ks[jj][d], s);
            float w = exp2f(fmaf(s, c1, -sl2 * (float)(j0 + jj)));
            l += w;
            #pragma unroll
            for (int d = 0; d < 64; ++d) o[d] = fmaf(w, Vs[jj][d], o[d]);
        }
    }

    const float inv = 1.0f / l;
    const size_t base = ((size_t)(b * 2048 + i)) * 1024 + h * 64;
    #pragma unroll
    for (int d0 = 0; d0 < 64; d0 += 8) {
        ushort_t pk[8];
        #pragma unroll
        for (int e = 0; e < 8; ++e) pk[e] = f2bf(o[d0 + e] * inv);
        *(uint4*)(AO + base + d0) = *(uint4*)pk;
    }
}

// ---------------- Output projection GEMM + bias -> FP32 output ----------------
__global__ __launch_bounds__(256) void oproj_gemm(
    const ushort_t* __restrict__ A, const void* __restrict__ W,
    const void* __restrict__ bias, float* __restrict__ out)
{
    __shared__ ushort_t As[64 * 40];
    __shared__ ushort_t Bs[64 * 40];

    const unsigned flag = detect_fp32(W);

    const int tid  = threadIdx.x;
    const int m0   = blockIdx.y * 64, n0 = blockIdx.x * 64;
    const int lane = tid & 63, wv = tid >> 6;
    const int quad = lane >> 4, l15 = lane & 15;
    const int wm = (wv & 1) * 32, wn = (wv >> 1) * 32;

    const int ar = tid >> 2, ac = (tid & 3) * 8;
    const int bk = tid >> 3, bc = (tid & 7) * 8;

    f32x4 acc[2][2] = {};

    uint4 ra = *(const uint4*)(A + (size_t)(m0 + ar) * 1024 + ac);
    uint4 rb = load8(W, (size_t)bk * 1024 + n0 + bc, flag);

    for (int kt = 0; kt < 32; ++kt) {
        __syncthreads();
        *(uint4*)(As + ar * 40 + ac) = ra;
        {
            const ushort_t* s = (const ushort_t*)&rb;
            #pragma unroll
            for (int i = 0; i < 8; ++i) Bs[(bc + i) * 40 + bk] = s[i];
        }
        __syncthreads();
        if (kt < 31) {
            int k0 = (kt + 1) * 32;
            ra = *(const uint4*)(A + (size_t)(m0 + ar) * 1024 + k0 + ac);
            rb = load8(W, (size_t)(k0 + bk) * 1024 + n0 + bc, flag);
        }
        bf16x8 af0 = *(const bf16x8*)(As + (wm + l15) * 40 + quad * 8);
        bf16x8 af1 = *(const bf16x8*)(As + (wm + 16 + l15) * 40 + quad * 8);
        bf16x8 bf0 = *(const bf16x8*)(Bs + (wn + l15) * 40 + quad * 8);
        bf16x8 bf1 = *(const bf16x8*)(Bs + (wn + 16 + l15) * 40 + quad * 8);
        acc[0][0] = MFMA_16x16x32(af0, bf0, acc[0][0]);
        acc[0][1] = MFMA_16x16x32(af0, bf1, acc[0][1]);
        acc[1][0] = MFMA_16x16x32(af1, bf0, acc[1][0]);
        acc[1][1] = MFMA_16x16x32(af1, bf1, acc[1][1]);
    }

    #pragma unroll
    for (int mm = 0; mm < 2; ++mm) {
        #pragma unroll
        for (int nn = 0; nn < 2; ++nn) {
            #pragma unroll
            for (int r = 0; r < 4; ++r) {
                int m = m0 + wm + mm * 16 + quad * 4 + r;
                int c = n0 + wn + nn * 16 + l15;
                float bv = flag ? ((const float*)bias)[c] : bf2f(((const ushort_t*)bias)[c]);
                out[(size_t)m * 1024 + c] = acc[mm][nn][r] + bv;   // FP32 store
            }
        }
    }
}

extern "C" void kernel_launch(void* const* d_in, const int* in_sizes, int n_in,
                              void* d_out, int out_size, void* d_ws, size_t ws_size,
                              hipStream_t stream) {
    const void* X  = d_in[0];
    const void* Wq = d_in[1];
    const void* Wk = d_in[2];
    const void* Wv = d_in[3];
    const void* Wo = d_in[4];
    const void* bo = d_in[5];

    const size_t M = 1024 * 1024;
    ushort_t* ws = (ushort_t*)d_ws;
    ushort_t* Qb = ws;            // 4M elems (8 MB)
    ushort_t* Kb = ws + 4 * M;
    ushort_t* Vb = ws + 8 * M;
    ushort_t* AO = ws + 12 * M;   // 32 MB total
    float* out = (float*)d_out;

    qkv_gemm<<<dim3(16, 64, 3), 256, 0, stream>>>(X, Wq, Wk, Wv, Qb, Kb, Vb);
    attn_simple<<<dim3(32, 8), 256, 0, stream>>>(Qb, Kb, Vb, AO);
    oproj_gemm<<<dim3(16, 64), 256, 0, stream>>>(AO, Wo, bo, out);
}

// Round 6
// 417.566 us; speedup vs baseline: 7.9649x; 7.9649x over previous
//
#include <hip/hip_runtime.h>
#include <hip/hip_bf16.h>

// B=2, N=2048, D=1024, H=16, DH=64. Output fp32 (verified R5); inputs runtime-
// detected fp32-vs-bf16 (detect_fp32 on weight words). R6 restores the MFMA
// attention (R3 pipeline, HW-verified correct via bit-identical-absmax evidence)
// in place of the latency-bound scalar attention (3108 us, VALUBusy 8%).
//
// ws (bf16 elems): Q[B][H][N][DH]@0, K@4M, Vt[B][H][DH][N]@8M, AO[B][N][H*DH]@12M.
// 32 MB total.

typedef __bf16 bf16x8 __attribute__((ext_vector_type(8)));
typedef unsigned short ushort8_t __attribute__((ext_vector_type(8)));
typedef float f32x4 __attribute__((ext_vector_type(4)));
typedef unsigned short ushort_t;

#define MFMA_16x16x32(a, b, c) __builtin_amdgcn_mfma_f32_16x16x32_bf16(a, b, c, 0, 0, 0)

__device__ __forceinline__ void mem_fence_compiler() { asm volatile("" ::: "memory"); }

__device__ __forceinline__ ushort_t f2bf(float f) {
    __hip_bfloat16 h = __float2bfloat16(f);
    return __builtin_bit_cast(ushort_t, h);
}
__device__ __forceinline__ float bf2f(ushort_t u) {
    unsigned x = ((unsigned)u) << 16;
    return __builtin_bit_cast(float, x);
}

// Wave-uniform dtype probe: weights ~N(0,0.02^2) -> bf16 words never have
// exp-field >= 0x7F; fp32 low-mantissa words ~uniform -> ~50% hit.
__device__ __forceinline__ unsigned detect_fp32(const void* wp) {
    const ushort_t* w = (const ushort_t*)wp;
    unsigned c = 0;
    #pragma unroll
    for (int i = 0; i < 128; ++i) c += (((w[i] >> 7) & 0xFF) >= 0x7F) ? 1u : 0u;
    return (c > 8) ? 1u : 0u;
}

// Load 8 consecutive elements (idx multiple of 8) as bf16 packed in uint4.
__device__ __forceinline__ uint4 load8(const void* p, size_t idx, unsigned flag) {
    if (flag) {
        const float* f = (const float*)p + idx;
        float4 a = *(const float4*)f;
        float4 b = *(const float4*)(f + 4);
        ushort_t u[8] = { f2bf(a.x), f2bf(a.y), f2bf(a.z), f2bf(a.w),
                          f2bf(b.x), f2bf(b.y), f2bf(b.z), f2bf(b.w) };
        return *(uint4*)u;
    }
    return *(const uint4*)((const ushort_t*)p + idx);
}

// ---------------- QKV projection GEMM ----------------
// grid (16 n-tiles, 64 m-tiles, 3 weights), block 256 (4 waves), 64x64 tile, BK=32.
// z=0 -> Q, z=1 -> K ([B][H][N][DH]); z=2 -> V transposed [B][H][DH][N].
__global__ __launch_bounds__(256) void qkv_gemm(
    const void* __restrict__ X, const void* __restrict__ Wq,
    const void* __restrict__ Wk, const void* __restrict__ Wv,
    ushort_t* __restrict__ Q, ushort_t* __restrict__ K, ushort_t* __restrict__ Vt)
{
    __shared__ ushort_t As[64 * 40];
    __shared__ ushort_t Bs[64 * 40];   // transposed: Bs[n][k]

    const unsigned flag = detect_fp32(Wq);
    const int z = blockIdx.z;
    const void* W = (z == 0) ? Wq : ((z == 1) ? Wk : Wv);

    const int tid  = threadIdx.x;
    const int m0   = blockIdx.y * 64, n0 = blockIdx.x * 64;
    const int lane = tid & 63, wv = tid >> 6;
    const int quad = lane >> 4, l15 = lane & 15;
    const int wm = (wv & 1) * 32, wn = (wv >> 1) * 32;

    const int ar = tid >> 2, ac = (tid & 3) * 8;
    const int bk = tid >> 3, bc = (tid & 7) * 8;

    f32x4 acc[2][2] = {};

    uint4 ra = load8(X, (size_t)(m0 + ar) * 1024 + ac, flag);
    uint4 rb = load8(W, (size_t)bk * 1024 + n0 + bc, flag);

    for (int kt = 0; kt < 32; ++kt) {
        __syncthreads();
        *(uint4*)(As + ar * 40 + ac) = ra;
        {
            const ushort_t* s = (const ushort_t*)&rb;
            #pragma unroll
            for (int i = 0; i < 8; ++i) Bs[(bc + i) * 40 + bk] = s[i];
        }
        __syncthreads();
        if (kt < 31) {
            int k0 = (kt + 1) * 32;
            ra = load8(X, (size_t)(m0 + ar) * 1024 + k0 + ac, flag);
            rb = load8(W, (size_t)(k0 + bk) * 1024 + n0 + bc, flag);
        }
        bf16x8 af0 = *(const bf16x8*)(As + (wm + l15) * 40 + quad * 8);
        bf16x8 af1 = *(const bf16x8*)(As + (wm + 16 + l15) * 40 + quad * 8);
        bf16x8 bf0 = *(const bf16x8*)(Bs + (wn + l15) * 40 + quad * 8);
        bf16x8 bf1 = *(const bf16x8*)(Bs + (wn + 16 + l15) * 40 + quad * 8);
        acc[0][0] = MFMA_16x16x32(af0, bf0, acc[0][0]);
        acc[0][1] = MFMA_16x16x32(af0, bf1, acc[0][1]);
        acc[1][0] = MFMA_16x16x32(af1, bf0, acc[1][0]);
        acc[1][1] = MFMA_16x16x32(af1, bf1, acc[1][1]);
    }

    // C/D layout: row=(quad*4+r), col=l15 within each 16x16 subtile.
    #pragma unroll
    for (int mm = 0; mm < 2; ++mm) {
        #pragma unroll
        for (int nn = 0; nn < 2; ++nn) {
            if (z == 2) {
                int c  = n0 + wn + nn * 16 + l15;
                int h  = c >> 6, dh = c & 63;
                int mA = m0 + wm + mm * 16 + quad * 4;
                int b  = mA >> 11, nseq = mA & 2047;
                ushort_t pk[4];
                #pragma unroll
                for (int r = 0; r < 4; ++r) pk[r] = f2bf(acc[mm][nn][r]);
                *(ushort2*)(Vt + ((size_t)((b * 16 + h) * 64 + dh)) * 2048 + nseq)     = *(ushort2*)&pk[0];
                *(ushort2*)(Vt + ((size_t)((b * 16 + h) * 64 + dh)) * 2048 + nseq + 2) = *(ushort2*)&pk[2];
            } else {
                ushort_t* dst = (z == 0) ? Q : K;
                #pragma unroll
                for (int r = 0; r < 4; ++r) {
                    int m = m0 + wm + mm * 16 + quad * 4 + r;
                    int c = n0 + wn + nn * 16 + l15;
                    int b = m >> 11, nseq = m & 2047;
                    int h = c >> 6, dh = c & 63;
                    dst[((size_t)((b * 16 + h) * 2048 + nseq)) * 64 + dh] = f2bf(acc[mm][nn][r]);
                }
            }
        }
    }
}

// ---------------- MFMA flash attention with ALiBi, causal ----------------
// grid (B*H=32, N/64=32), block 256 = 4 independent waves; wave owns 16 q-rows.
// Fixed shift m_i = slope*i: weight = exp2(qk*c1 - sl2*j); bias = +slope*(i-j)
// per reference (max at j=0) -> bounded, l > 0 always. Row-sum l via MFMA
// against all-ones B fragment. P C-layout -> A-layout via volatile LDS
// round-trip (HW-verified correct in R3).
__global__ __launch_bounds__(256) void attn_kernel(
    const ushort_t* __restrict__ Q, const ushort_t* __restrict__ K,
    const ushort_t* __restrict__ Vt, ushort_t* __restrict__ AO)
{
    __shared__ ushort_t P[4][16 * 40];   // per-wave P tile [16 q-rows][32 j-cols]

    const int tid  = threadIdx.x;
    const int wv   = tid >> 6, lane = tid & 63;
    const int quad = lane >> 4, l15 = lane & 15;
    const int bh   = blockIdx.x;
    const int h    = bh & 15, b = bh >> 4;
    const int qbase = blockIdx.y * 64 + wv * 16;

    const ushort_t* Qh = Q  + (size_t)bh * 2048 * 64;
    const ushort_t* Kh = K  + (size_t)bh * 2048 * 64;
    const ushort_t* Vh = Vt + (size_t)bh * 64 * 2048;
    volatile ushort_t* Pw = P[wv];

    const float LOG2E = 1.44269504088896340736f;
    const float sl2 = exp2f(-0.5f * (float)(h + 1)) * LOG2E;   // slope*log2e
    const float c1  = 0.125f * LOG2E;                          // DH^-0.5*log2e

    bf16x8 q0 = *(const bf16x8*)(Qh + (size_t)(qbase + l15) * 64 + quad * 8);
    bf16x8 q1 = *(const bf16x8*)(Qh + (size_t)(qbase + l15) * 64 + 32 + quad * 8);

    bf16x8 ones;
    #pragma unroll
    for (int i = 0; i < 8; ++i) ones[i] = (__bf16)1.0f;

    f32x4 accv[4] = {};
    f32x4 accl = {};

    const int irow = qbase + quad * 4;
    const int jt_n = (qbase + 15) / 32 + 1;

    for (int jt = 0; jt < jt_n; ++jt) {
        const int j0 = jt * 32;
        f32x4 s0 = {}, s1 = {};
        {
            bf16x8 k00 = *(const bf16x8*)(Kh + (size_t)(j0 + l15) * 64 + quad * 8);
            bf16x8 k01 = *(const bf16x8*)(Kh + (size_t)(j0 + l15) * 64 + 32 + quad * 8);
            bf16x8 k10 = *(const bf16x8*)(Kh + (size_t)(j0 + 16 + l15) * 64 + quad * 8);
            bf16x8 k11 = *(const bf16x8*)(Kh + (size_t)(j0 + 16 + l15) * 64 + 32 + quad * 8);
            s0 = MFMA_16x16x32(q0, k00, s0);
            s0 = MFMA_16x16x32(q1, k01, s0);
            s1 = MFMA_16x16x32(q0, k10, s1);
            s1 = MFMA_16x16x32(q1, k11, s1);
        }
        // V b-fragments hoisted: global-load latency overlaps exp2/pack VALU.
        bf16x8 vf[4];
        #pragma unroll
        for (int dt = 0; dt < 4; ++dt)
            vf[dt] = *(const bf16x8*)(Vh + (size_t)(dt * 16 + l15) * 2048 + j0 + quad * 8);

        const int jc0 = j0 + l15, jc1 = j0 + 16 + l15;
        const float off0 = -sl2 * (float)jc0;
        const float off1 = -sl2 * (float)jc1;
        #pragma unroll
        for (int r = 0; r < 4; ++r) {
            int i = irow + r;
            float p0 = (jc0 <= i) ? exp2f(fmaf(s0[r], c1, off0)) : 0.0f;
            float p1 = (jc1 <= i) ? exp2f(fmaf(s1[r], c1, off1)) : 0.0f;
            Pw[(quad * 4 + r) * 40 + l15]      = f2bf(p0);
            Pw[(quad * 4 + r) * 40 + 16 + l15] = f2bf(p1);
        }
        mem_fence_compiler();
        ushort8_t pr;
        #pragma unroll
        for (int t = 0; t < 8; ++t) pr[t] = Pw[l15 * 40 + quad * 8 + t];
        mem_fence_compiler();
        bf16x8 pf = __builtin_bit_cast(bf16x8, pr);

        accl = MFMA_16x16x32(pf, ones, accl);
        #pragma unroll
        for (int dt = 0; dt < 4; ++dt)
            accv[dt] = MFMA_16x16x32(pf, vf[dt], accv[dt]);
    }

    #pragma unroll
    for (int r = 0; r < 4; ++r) {
        float inv = 1.0f / fmaxf(accl[r], 1e-30f);
        int i = irow + r;
        size_t base = ((size_t)(b * 2048 + i)) * 1024 + h * 64;
        #pragma unroll
        for (int dt = 0; dt < 4; ++dt)
            AO[base + dt * 16 + l15] = f2bf(accv[dt][r] * inv);
    }
}

// ---------------- Output projection GEMM + bias -> FP32 output ----------------
__global__ __launch_bounds__(256) void oproj_gemm(
    const ushort_t* __restrict__ A, const void* __restrict__ W,
    const void* __restrict__ bias, float* __restrict__ out)
{
    __shared__ ushort_t As[64 * 40];
    __shared__ ushort_t Bs[64 * 40];

    const unsigned flag = detect_fp32(W);

    const int tid  = threadIdx.x;
    const int m0   = blockIdx.y * 64, n0 = blockIdx.x * 64;
    const int lane = tid & 63, wv = tid >> 6;
    const int quad = lane >> 4, l15 = lane & 15;
    const int wm = (wv & 1) * 32, wn = (wv >> 1) * 32;

    const int ar = tid >> 2, ac = (tid & 3) * 8;
    const int bk = tid >> 3, bc = (tid & 7) * 8;

    f32x4 acc[2][2] = {};

    uint4 ra = *(const uint4*)(A + (size_t)(m0 + ar) * 1024 + ac);
    uint4 rb = load8(W, (size_t)bk * 1024 + n0 + bc, flag);

    for (int kt = 0; kt < 32; ++kt) {
        __syncthreads();
        *(uint4*)(As + ar * 40 + ac) = ra;
        {
            const ushort_t* s = (const ushort_t*)&rb;
            #pragma unroll
            for (int i = 0; i < 8; ++i) Bs[(bc + i) * 40 + bk] = s[i];
        }
        __syncthreads();
        if (kt < 31) {
            int k0 = (kt + 1) * 32;
            ra = *(const uint4*)(A + (size_t)(m0 + ar) * 1024 + k0 + ac);
            rb = load8(W, (size_t)(k0 + bk) * 1024 + n0 + bc, flag);
        }
        bf16x8 af0 = *(const bf16x8*)(As + (wm + l15) * 40 + quad * 8);
        bf16x8 af1 = *(const bf16x8*)(As + (wm + 16 + l15) * 40 + quad * 8);
        bf16x8 bf0 = *(const bf16x8*)(Bs + (wn + l15) * 40 + quad * 8);
        bf16x8 bf1 = *(const bf16x8*)(Bs + (wn + 16 + l15) * 40 + quad * 8);
        acc[0][0] = MFMA_16x16x32(af0, bf0, acc[0][0]);
        acc[0][1] = MFMA_16x16x32(af0, bf1, acc[0][1]);
        acc[1][0] = MFMA_16x16x32(af1, bf0, acc[1][0]);
        acc[1][1] = MFMA_16x16x32(af1, bf1, acc[1][1]);
    }

    #pragma unroll
    for (int mm = 0; mm < 2; ++mm) {
        #pragma unroll
        for (int nn = 0; nn < 2; ++nn) {
            #pragma unroll
            for (int r = 0; r < 4; ++r) {
                int m = m0 + wm + mm * 16 + quad * 4 + r;
                int c = n0 + wn + nn * 16 + l15;
                float bv = flag ? ((const float*)bias)[c] : bf2f(((const ushort_t*)bias)[c]);
                out[(size_t)m * 1024 + c] = acc[mm][nn][r] + bv;   // FP32 store
            }
        }
    }
}

extern "C" void kernel_launch(void* const* d_in, const int* in_sizes, int n_in,
                              void* d_out, int out_size, void* d_ws, size_t ws_size,
                              hipStream_t stream) {
    const void* X  = d_in[0];
    const void* Wq = d_in[1];
    const void* Wk = d_in[2];
    const void* Wv = d_in[3];
    const void* Wo = d_in[4];
    const void* bo = d_in[5];

    const size_t M = 1024 * 1024;
    ushort_t* ws = (ushort_t*)d_ws;
    ushort_t* Qb = ws;            // 4M elems (8 MB)
    ushort_t* Kb = ws + 4 * M;
    ushort_t* Vt = ws + 8 * M;
    ushort_t* AO = ws + 12 * M;   // 32 MB total
    float* out = (float*)d_out;

    qkv_gemm<<<dim3(16, 64, 3), 256, 0, stream>>>(X, Wq, Wk, Wv, Qb, Kb, Vt);
    attn_kernel<<<dim3(32, 32), 256, 0, stream>>>(Qb, Kb, Vt, AO);
    oproj_gemm<<<dim3(16, 64), 256, 0, stream>>>(AO, Wo, bo, out);
}

// Round 7
// 348.879 us; speedup vs baseline: 9.5330x; 1.1969x over previous
//
#include <hip/hip_runtime.h>
#include <hip/hip_bf16.h>

// B=2, N=2048, D=1024, H=16, DH=64. Output fp32 (HW-verified R5); inputs
// runtime-detected fp32-vs-bf16. R7: (1) attn P round-trip via packed-uint LDS
// (no volatile serialization), (2) causal load-balance strip remap,
// (3) 128x128 GEMM tiles (m93 ladder pattern).
//
// ws (bf16 elems): Q[B][H][N][DH]@0, K@4M, Vt[B][H][DH][N]@8M, AO[B][N][H*DH]@12M.

typedef __bf16 bf16x8 __attribute__((ext_vector_type(8)));
typedef float f32x4 __attribute__((ext_vector_type(4)));
typedef unsigned short ushort_t;

#define MFMA_16x16x32(a, b, c) __builtin_amdgcn_mfma_f32_16x16x32_bf16(a, b, c, 0, 0, 0)

__device__ __forceinline__ void mem_fence_compiler() { asm volatile("" ::: "memory"); }

__device__ __forceinline__ ushort_t f2bf(float f) {
    __hip_bfloat16 h = __float2bfloat16(f);
    return __builtin_bit_cast(ushort_t, h);
}
__device__ __forceinline__ float bf2f(ushort_t u) {
    unsigned x = ((unsigned)u) << 16;
    return __builtin_bit_cast(float, x);
}

// Wave-uniform dtype probe: weights ~N(0,0.02^2) -> bf16 words never have
// exp-field >= 0x7F; fp32 low-mantissa words ~uniform -> ~50% hit.
__device__ __forceinline__ unsigned detect_fp32(const void* wp) {
    const ushort_t* w = (const ushort_t*)wp;
    unsigned c = 0;
    #pragma unroll
    for (int i = 0; i < 128; ++i) c += (((w[i] >> 7) & 0xFF) >= 0x7F) ? 1u : 0u;
    return (c > 8) ? 1u : 0u;
}

// Load 8 consecutive elements (idx multiple of 8) as bf16 packed in uint4.
__device__ __forceinline__ uint4 load8(const void* p, size_t idx, unsigned flag) {
    if (flag) {
        const float* f = (const float*)p + idx;
        float4 a = *(const float4*)f;
        float4 b = *(const float4*)(f + 4);
        ushort_t u[8] = { f2bf(a.x), f2bf(a.y), f2bf(a.z), f2bf(a.w),
                          f2bf(b.x), f2bf(b.y), f2bf(b.z), f2bf(b.w) };
        return *(uint4*)u;
    }
    return *(const uint4*)((const ushort_t*)p + idx);
}

// ---------------- QKV projection GEMM, 128x128 tile ----------------
// grid (8 n-tiles, 32 m-tiles, 3 weights), block 256 (4 waves), BK=32.
// Wave quadrant 64x64: acc[4][4]. z=0->Q, z=1->K ([B][H][N][DH]); z=2->Vt.
__global__ __launch_bounds__(256) void qkv_gemm(
    const void* __restrict__ X, const void* __restrict__ Wq,
    const void* __restrict__ Wk, const void* __restrict__ Wv,
    ushort_t* __restrict__ Q, ushort_t* __restrict__ K, ushort_t* __restrict__ Vt)
{
    __shared__ ushort_t As[128 * 40];
    __shared__ ushort_t Bs[128 * 40];   // transposed: Bs[n][k]

    const unsigned flag = detect_fp32(Wq);
    const int z = blockIdx.z;
    const void* W = (z == 0) ? Wq : ((z == 1) ? Wk : Wv);

    const int tid  = threadIdx.x;
    const int m0   = blockIdx.y * 128, n0 = blockIdx.x * 128;
    const int lane = tid & 63, wv = tid >> 6;
    const int quad = lane >> 4, l15 = lane & 15;
    const int wm = (wv & 1) * 64, wn = (wv >> 1) * 64;

    const int ar = tid >> 1, ac = (tid & 1) * 16;   // A: 128 rows x 32 k
    const int bk = tid >> 3, bc = (tid & 7) * 16;   // B: 32 k x 128 n

    f32x4 acc[4][4] = {};

    uint4 ra0 = load8(X, (size_t)(m0 + ar) * 1024 + ac,     flag);
    uint4 ra1 = load8(X, (size_t)(m0 + ar) * 1024 + ac + 8, flag);
    uint4 rb0 = load8(W, (size_t)bk * 1024 + n0 + bc,     flag);
    uint4 rb1 = load8(W, (size_t)bk * 1024 + n0 + bc + 8, flag);

    for (int kt = 0; kt < 32; ++kt) {
        __syncthreads();
        *(uint4*)(As + ar * 40 + ac)     = ra0;
        *(uint4*)(As + ar * 40 + ac + 8) = ra1;
        {
            const ushort_t* s0 = (const ushort_t*)&rb0;
            const ushort_t* s1 = (const ushort_t*)&rb1;
            #pragma unroll
            for (int i = 0; i < 8; ++i) {
                Bs[(bc + i) * 40 + bk]     = s0[i];
                Bs[(bc + 8 + i) * 40 + bk] = s1[i];
            }
        }
        __syncthreads();
        if (kt < 31) {
            int k0 = (kt + 1) * 32;
            ra0 = load8(X, (size_t)(m0 + ar) * 1024 + k0 + ac,     flag);
            ra1 = load8(X, (size_t)(m0 + ar) * 1024 + k0 + ac + 8, flag);
            rb0 = load8(W, (size_t)(k0 + bk) * 1024 + n0 + bc,     flag);
            rb1 = load8(W, (size_t)(k0 + bk) * 1024 + n0 + bc + 8, flag);
        }
        bf16x8 af[4], bfr[4];
        #pragma unroll
        for (int t = 0; t < 4; ++t) {
            af[t]  = *(const bf16x8*)(As + (wm + t * 16 + l15) * 40 + quad * 8);
            bfr[t] = *(const bf16x8*)(Bs + (wn + t * 16 + l15) * 40 + quad * 8);
        }
        #pragma unroll
        for (int mt = 0; mt < 4; ++mt)
            #pragma unroll
            for (int nt = 0; nt < 4; ++nt)
                acc[mt][nt] = MFMA_16x16x32(af[mt], bfr[nt], acc[mt][nt]);
    }

    // C/D layout: row=(quad*4+r), col=l15 within each 16x16 subtile.
    #pragma unroll
    for (int mt = 0; mt < 4; ++mt) {
        #pragma unroll
        for (int nt = 0; nt < 4; ++nt) {
            if (z == 2) {
                int c  = n0 + wn + nt * 16 + l15;
                int h  = c >> 6, dh = c & 63;
                int mA = m0 + wm + mt * 16 + quad * 4;
                int b  = mA >> 11, nseq = mA & 2047;
                ushort_t pk[4];
                #pragma unroll
                for (int r = 0; r < 4; ++r) pk[r] = f2bf(acc[mt][nt][r]);
                *(ushort2*)(Vt + ((size_t)((b * 16 + h) * 64 + dh)) * 2048 + nseq)     = *(ushort2*)&pk[0];
                *(ushort2*)(Vt + ((size_t)((b * 16 + h) * 64 + dh)) * 2048 + nseq + 2) = *(ushort2*)&pk[2];
            } else {
                ushort_t* dst = (z == 0) ? Q : K;
                #pragma unroll
                for (int r = 0; r < 4; ++r) {
                    int m = m0 + wm + mt * 16 + quad * 4 + r;
                    int c = n0 + wn + nt * 16 + l15;
                    int b = m >> 11, nseq = m & 2047;
                    int h = c >> 6, dh = c & 63;
                    dst[((size_t)((b * 16 + h) * 2048 + nseq)) * 64 + dh] = f2bf(acc[mt][nt][r]);
                }
            }
        }
    }
}

// ---------------- MFMA flash attention with ALiBi, causal ----------------
// grid (B*H=32, 32), block 256 = 4 waves. Wave-global index W=blockIdx.y*4+wv
// in [0,128); strip = (W&1) ? 127-(W>>1) : W>>1 pairs long+short causal strips
// in one block (uniform work). Wave owns q-rows strip*16..+15.
// P C-layout -> A-layout via packed-uint LDS: word c of a row = cols (c, c+16).
__global__ __launch_bounds__(256) void attn_kernel(
    const ushort_t* __restrict__ Q, const ushort_t* __restrict__ K,
    const ushort_t* __restrict__ Vt, ushort_t* __restrict__ AO)
{
    __shared__ unsigned Pu[4][16 * 18];   // per-wave [16 rows][16 words], stride 18

    const int tid  = threadIdx.x;
    const int wv   = tid >> 6, lane = tid & 63;
    const int quad = lane >> 4, l15 = lane & 15;
    const int bh   = blockIdx.x;
    const int h    = bh & 15, b = bh >> 4;

    const int Wg    = blockIdx.y * 4 + wv;           // 0..127
    const int p     = Wg >> 1;
    const int strip = (Wg & 1) ? (127 - p) : p;
    const int qbase = strip * 16;

    const ushort_t* Qh = Q  + (size_t)bh * 2048 * 64;
    const ushort_t* Kh = K  + (size_t)bh * 2048 * 64;
    const ushort_t* Vh = Vt + (size_t)bh * 64 * 2048;
    unsigned* Pw = Pu[wv];

    const float LOG2E = 1.44269504088896340736f;
    const float sl2 = exp2f(-0.5f * (float)(h + 1)) * LOG2E;   // slope*log2e
    const float c1  = 0.125f * LOG2E;                          // DH^-0.5*log2e

    bf16x8 q0 = *(const bf16x8*)(Qh + (size_t)(qbase + l15) * 64 + quad * 8);
    bf16x8 q1 = *(const bf16x8*)(Qh + (size_t)(qbase + l15) * 64 + 32 + quad * 8);

    bf16x8 ones;
    #pragma unroll
    for (int i = 0; i < 8; ++i) ones[i] = (__bf16)1.0f;

    f32x4 accv[4] = {};
    f32x4 accl = {};

    const int irow = qbase + quad * 4;
    const int jt_n = (qbase + 15) / 32 + 1;

    for (int jt = 0; jt < jt_n; ++jt) {
        const int j0 = jt * 32;
        f32x4 s0 = {}, s1 = {};
        {
            bf16x8 k00 = *(const bf16x8*)(Kh + (size_t)(j0 + l15) * 64 + quad * 8);
            bf16x8 k01 = *(const bf16x8*)(Kh + (size_t)(j0 + l15) * 64 + 32 + quad * 8);
            bf16x8 k10 = *(const bf16x8*)(Kh + (size_t)(j0 + 16 + l15) * 64 + quad * 8);
            bf16x8 k11 = *(const bf16x8*)(Kh + (size_t)(j0 + 16 + l15) * 64 + 32 + quad * 8);
            s0 = MFMA_16x16x32(q0, k00, s0);
            s0 = MFMA_16x16x32(q1, k01, s0);
            s1 = MFMA_16x16x32(q0, k10, s1);
            s1 = MFMA_16x16x32(q1, k11, s1);
        }
        // V b-fragments hoisted: global-load latency overlaps exp2/pack VALU.
        bf16x8 vf[4];
        #pragma unroll
        for (int dt = 0; dt < 4; ++dt)
            vf[dt] = *(const bf16x8*)(Vh + (size_t)(dt * 16 + l15) * 2048 + j0 + quad * 8);

        const int jc0 = j0 + l15, jc1 = j0 + 16 + l15;
        const float off0 = -sl2 * (float)jc0;
        const float off1 = -sl2 * (float)jc1;
        // Store: word l15 of row quad*4+r = (bf16(p0) | bf16(p1)<<16), cols (l15, l15+16).
        #pragma unroll
        for (int r = 0; r < 4; ++r) {
            int i = irow + r;
            float p0 = (jc0 <= i) ? exp2f(fmaf(s0[r], c1, off0)) : 0.0f;
            float p1 = (jc1 <= i) ? exp2f(fmaf(s1[r], c1, off1)) : 0.0f;
            Pw[(quad * 4 + r) * 18 + l15] = (unsigned)f2bf(p0) | ((unsigned)f2bf(p1) << 16);
        }
        mem_fence_compiler();
        // Read: row l15, cols quad*8..+7 = words (quad&1)*8+{0..7}, half quad>>1.
        {
            const int q8 = (quad & 1) * 8;
            const int sh = (quad >> 1) * 16;
            unsigned w[8];
            #pragma unroll
            for (int jx = 0; jx < 8; ++jx) w[jx] = Pw[l15 * 18 + q8 + jx];
            unsigned d[4];
            #pragma unroll
            for (int jx = 0; jx < 4; ++jx) {
                unsigned e0 = (w[2 * jx]     >> sh) & 0xFFFFu;
                unsigned e1 = (w[2 * jx + 1] >> sh) & 0xFFFFu;
                d[jx] = e0 | (e1 << 16);
            }
            bf16x8 pf = __builtin_bit_cast(bf16x8, *(uint4*)d);

            accl = MFMA_16x16x32(pf, ones, accl);
            #pragma unroll
            for (int dt = 0; dt < 4; ++dt)
                accv[dt] = MFMA_16x16x32(pf, vf[dt], accv[dt]);
        }
    }

    #pragma unroll
    for (int r = 0; r < 4; ++r) {
        float inv = 1.0f / fmaxf(accl[r], 1e-30f);
        int i = irow + r;
        size_t base = ((size_t)(b * 2048 + i)) * 1024 + h * 64;
        #pragma unroll
        for (int dt = 0; dt < 4; ++dt)
            AO[base + dt * 16 + l15] = f2bf(accv[dt][r] * inv);
    }
}

// ---------------- Output projection GEMM + bias, 128x128 tile -> FP32 ----------------
__global__ __launch_bounds__(256) void oproj_gemm(
    const ushort_t* __restrict__ A, const void* __restrict__ W,
    const void* __restrict__ bias, float* __restrict__ out)
{
    __shared__ ushort_t As[128 * 40];
    __shared__ ushort_t Bs[128 * 40];

    const unsigned flag = detect_fp32(W);

    const int tid  = threadIdx.x;
    const int m0   = blockIdx.y * 128, n0 = blockIdx.x * 128;
    const int lane = tid & 63, wv = tid >> 6;
    const int quad = lane >> 4, l15 = lane & 15;
    const int wm = (wv & 1) * 64, wn = (wv >> 1) * 64;

    const int ar = tid >> 1, ac = (tid & 1) * 16;
    const int bk = tid >> 3, bc = (tid & 7) * 16;

    f32x4 acc[4][4] = {};

    uint4 ra0 = *(const uint4*)(A + (size_t)(m0 + ar) * 1024 + ac);
    uint4 ra1 = *(const uint4*)(A + (size_t)(m0 + ar) * 1024 + ac + 8);
    uint4 rb0 = load8(W, (size_t)bk * 1024 + n0 + bc,     flag);
    uint4 rb1 = load8(W, (size_t)bk * 1024 + n0 + bc + 8, flag);

    for (int kt = 0; kt < 32; ++kt) {
        __syncthreads();
        *(uint4*)(As + ar * 40 + ac)     = ra0;
        *(uint4*)(As + ar * 40 + ac + 8) = ra1;
        {
            const ushort_t* s0 = (const ushort_t*)&rb0;
            const ushort_t* s1 = (const ushort_t*)&rb1;
            #pragma unroll
            for (int i = 0; i < 8; ++i) {
                Bs[(bc + i) * 40 + bk]     = s0[i];
                Bs[(bc + 8 + i) * 40 + bk] = s1[i];
            }
        }
        __syncthreads();
        if (kt < 31) {
            int k0 = (kt + 1) * 32;
            ra0 = *(const uint4*)(A + (size_t)(m0 + ar) * 1024 + k0 + ac);
            ra1 = *(const uint4*)(A + (size_t)(m0 + ar) * 1024 + k0 + ac + 8);
            rb0 = load8(W, (size_t)(k0 + bk) * 1024 + n0 + bc,     flag);
            rb1 = load8(W, (size_t)(k0 + bk) * 1024 + n0 + bc + 8, flag);
        }
        bf16x8 af[4], bfr[4];
        #pragma unroll
        for (int t = 0; t < 4; ++t) {
            af[t]  = *(const bf16x8*)(As + (wm + t * 16 + l15) * 40 + quad * 8);
            bfr[t] = *(const bf16x8*)(Bs + (wn + t * 16 + l15) * 40 + quad * 8);
        }
        #pragma unroll
        for (int mt = 0; mt < 4; ++mt)
            #pragma unroll
            for (int nt = 0; nt < 4; ++nt)
                acc[mt][nt] = MFMA_16x16x32(af[mt], bfr[nt], acc[mt][nt]);
    }

    #pragma unroll
    for (int mt = 0; mt < 4; ++mt) {
        #pragma unroll
        for (int nt = 0; nt < 4; ++nt) {
            #pragma unroll
            for (int r = 0; r < 4; ++r) {
                int m = m0 + wm + mt * 16 + quad * 4 + r;
                int c = n0 + wn + nt * 16 + l15;
                float bv = flag ? ((const float*)bias)[c] : bf2f(((const ushort_t*)bias)[c]);
                out[(size_t)m * 1024 + c] = acc[mt][nt][r] + bv;   // FP32 store
            }
        }
    }
}

extern "C" void kernel_launch(void* const* d_in, const int* in_sizes, int n_in,
                              void* d_out, int out_size, void* d_ws, size_t ws_size,
                              hipStream_t stream) {
    const void* X  = d_in[0];
    const void* Wq = d_in[1];
    const void* Wk = d_in[2];
    const void* Wv = d_in[3];
    const void* Wo = d_in[4];
    const void* bo = d_in[5];

    const size_t M = 1024 * 1024;
    ushort_t* ws = (ushort_t*)d_ws;
    ushort_t* Qb = ws;            // 4M elems (8 MB)
    ushort_t* Kb = ws + 4 * M;
    ushort_t* Vt = ws + 8 * M;
    ushort_t* AO = ws + 12 * M;   // 32 MB total
    float* out = (float*)d_out;

    qkv_gemm<<<dim3(8, 32, 3), 256, 0, stream>>>(X, Wq, Wk, Wv, Qb, Kb, Vt);
    attn_kernel<<<dim3(32, 32), 256, 0, stream>>>(Qb, Kb, Vt, AO);
    oproj_gemm<<<dim3(8, 32), 256, 0, stream>>>(AO, Wo, bo, out);
}